// Round 1
// baseline (1488.175 us; speedup 1.0000x reference)
//
#include <hip/hip_runtime.h>

typedef _Float16 half8 __attribute__((ext_vector_type(8)));
typedef _Float16 half4 __attribute__((ext_vector_type(4)));
typedef float floatx16 __attribute__((ext_vector_type(16)));

#define MFMA(a, b, c) __builtin_amdgcn_mfma_f32_32x32x16_f16(a, b, c, 0, 0, 0)

// Problem constants
#define NB   256
#define NF   512
#define NR   196
#define NI   1000
#define NV   300
#define IPAD 1024   // i padded to 1024 (16 tiles of 64)

// LDS strides (halves)
#define B1S 24      // Buf1 [224][24]  (16 f + 8 pad)
#define PS  232     // P    [64][232]
#define HS  232     // Hv   [64][232]

// -------------------- kernel 1: q = vecs @ w_g, split into fp16 hi/lo --------------------
__global__ __launch_bounds__(256) void qsplit_kernel(
    const float* __restrict__ vecs, const float* __restrict__ wg,
    _Float16* __restrict__ qh, _Float16* __restrict__ ql) {
    const int t = threadIdx.x;
    const int i0 = blockIdx.x * 8;
    __shared__ float vec[8][NV];
    for (int idx = t; idx < 8 * NV; idx += 256) {
        int ii = idx / NV;
        int v = idx - ii * NV;
        int i = i0 + ii;
        vec[ii][v] = (i < NI) ? vecs[(size_t)i * NV + v] : 0.0f;
    }
    __syncthreads();
    float acc[8][2];
#pragma unroll
    for (int ii = 0; ii < 8; ++ii) { acc[ii][0] = 0.f; acc[ii][1] = 0.f; }
#pragma unroll 4
    for (int v = 0; v < NV; ++v) {
        float w0 = wg[(size_t)v * NF + t];
        float w1 = wg[(size_t)v * NF + t + 256];
#pragma unroll
        for (int ii = 0; ii < 8; ++ii) {
            float x = vec[ii][v];
            acc[ii][0] += x * w0;
            acc[ii][1] += x * w1;
        }
    }
#pragma unroll
    for (int ii = 0; ii < 8; ++ii) {
        size_t i = i0 + ii;
        float q0 = acc[ii][0];
        float q1 = acc[ii][1];
        _Float16 h0 = (_Float16)q0;
        _Float16 h1 = (_Float16)q1;
        qh[i * NF + t]       = h0;
        qh[i * NF + t + 256] = h1;
        ql[i * NF + t]       = (_Float16)(q0 - (float)h0);
        ql[i * NF + t + 256] = (_Float16)(q1 - (float)h1);
    }
}

// -------------------- kernel 2: fused  S = q.h  -> softmax -> E = P.h^T --------------------
// grid (16, 256): blockIdx.x = i-tile (64 rows), blockIdx.y = b. block = 256 (4 waves).
// wave w: mt = w>>1 (i rows 32*mt..+32), rh = w&1 (r-tiles: rh0 -> 0..3, rh1 -> 4..6)
__global__ __launch_bounds__(256, 2) void attn_kernel(
    const float* __restrict__ H, const _Float16* __restrict__ qh,
    const _Float16* __restrict__ ql, float* __restrict__ out) {
    __shared__ __align__(16) char smem[60416];
    _Float16* Bh = (_Float16*)smem;                  // [224][24] stage-1 hi (union w/ Hv)
    _Float16* Bl = Bh + 224 * B1S;                   // [224][24] stage-1 lo (union w/ Hv)
    _Float16* Hv = (_Float16*)smem;                  // [64][232] stage-3 h (fp16)
    _Float16* P  = (_Float16*)(smem + 29696);        // [64][232] softmax probs
    float* mp = (float*)(smem + 59392);              // [2][64] partial max
    float* lp = mp + 128;                            // [2][64] partial sum

    const int tid  = threadIdx.x;
    const int lane = tid & 63;
    const int w    = tid >> 6;
    const int col  = lane & 31;   // n (r or f within 32-tile); also m for A-frags
    const int hf   = lane >> 5;   // k-half selector
    const int mt   = w >> 1;
    const int rh   = w & 1;
    const int t0   = rh * 4;
    const int ntile = rh ? 3 : 4;
    const int b = blockIdx.y;
    const int i_base = blockIdx.x * 64;

    const float* Hb = H + (size_t)b * NF * NR;

    floatx16 acc[4];
#pragma unroll
    for (int t = 0; t < 4; ++t)
#pragma unroll
        for (int k = 0; k < 16; ++k) acc[t][k] = 0.0f;

    const size_t qoff = (size_t)(i_base + 32 * mt + col) * NF;

    // ---------------- stage 1: S = (qh+ql).(hh+hl), K-loop over f in chunks of 16 ----------------
    for (int c = 0; c < 32; ++c) {
        __syncthreads();
        // stage 16 f-rows of h, transposed to [r][f], split hi/lo
        for (int idx = tid; idx < 4 * NR; idx += 256) {
            int fg = idx / NR;          // 0..3 (group of 4 f)
            int r  = idx - fg * NR;     // 0..195
            const float* hp = Hb + (size_t)(c * 16 + fg * 4) * NR + r;
            float x0 = hp[0], x1 = hp[NR], x2 = hp[2 * NR], x3 = hp[3 * NR];
            _Float16 a0 = (_Float16)x0, a1 = (_Float16)x1, a2 = (_Float16)x2, a3 = (_Float16)x3;
            half4 hi = {a0, a1, a2, a3};
            half4 lo = {(_Float16)(x0 - (float)a0), (_Float16)(x1 - (float)a1),
                        (_Float16)(x2 - (float)a2), (_Float16)(x3 - (float)a3)};
            *(half4*)&Bh[r * B1S + fg * 4] = hi;
            *(half4*)&Bl[r * B1S + fg * 4] = lo;
        }
        __syncthreads();
        // compute: A-frags from global q (L2-hot), B-frags from LDS
        half8 a_h = *(const half8*)(qh + qoff + c * 16 + hf * 8);
        half8 a_l = *(const half8*)(ql + qoff + c * 16 + hf * 8);
#pragma unroll
        for (int t = 0; t < 4; ++t) {
            if (t < ntile) {
                int r = (t0 + t) * 32 + col;
                half8 b_h = *(const half8*)&Bh[r * B1S + hf * 8];
                half8 b_l = *(const half8*)&Bl[r * B1S + hf * 8];
                acc[t] = MFMA(a_h, b_h, acc[t]);
                acc[t] = MFMA(a_l, b_h, acc[t]);
                acc[t] = MFMA(a_h, b_l, acc[t]);
            }
        }
    }

    // ---------------- stage 2: softmax over r (split across rh wave pairs) ----------------
    float mx[16], sv[16];
#pragma unroll
    for (int j = 0; j < 16; ++j) {
        float m = -3.0e38f;
#pragma unroll
        for (int t = 0; t < 4; ++t) {
            if (t < ntile) {
                int r = (t0 + t) * 32 + col;
                float v = acc[t][j];
                if (r < NR) m = fmaxf(m, v);
            }
        }
#pragma unroll
        for (int s = 1; s < 32; s <<= 1) m = fmaxf(m, __shfl_xor(m, s));
        float l = 0.0f;
#pragma unroll
        for (int t = 0; t < 4; ++t) {
            if (t < ntile) {
                int r = (t0 + t) * 32 + col;
                if (r < NR) l += __expf(acc[t][j] - m);
            }
        }
#pragma unroll
        for (int s = 1; s < 32; s <<= 1) l += __shfl_xor(l, s);
        mx[j] = m;
        sv[j] = l;
    }
    if (col == 0) {
#pragma unroll
        for (int j = 0; j < 16; ++j) {
            int row = 32 * mt + (j & 3) + 8 * (j >> 2) + 4 * hf;
            mp[rh * 64 + row] = mx[j];
            lp[rh * 64 + row] = sv[j];
        }
    }
    __syncthreads();
#pragma unroll
    for (int j = 0; j < 16; ++j) {
        int row = 32 * mt + (j & 3) + 8 * (j >> 2) + 4 * hf;
        float m0 = mp[row], m1 = mp[64 + row];
        float l0 = lp[row], l1 = lp[64 + row];
        float M = fmaxf(m0, m1);
        float L = l0 * __expf(m0 - M) + l1 * __expf(m1 - M);
        float inv = 1.0f / L;
#pragma unroll
        for (int t = 0; t < 4; ++t) {
            if (t < ntile) {
                int r = (t0 + t) * 32 + col;
                float p = (r < NR) ? __expf(acc[t][j] - M) * inv : 0.0f;
                P[row * PS + r] = (_Float16)p;
            }
        }
    }

    // ---------------- stage 3: E = P . h^T, loop f in chunks of 64 ----------------
    const int myf = rh * 32 + col;  // n within 64-f chunk for this wave
    for (int fc = 0; fc < 8; ++fc) {
        __syncthreads();  // P ready (fc=0) / previous chunk's reads done
        for (int idx = tid; idx < 64 * 49; idx += 256) {
            int fl = idx / 49;
            int r4 = (idx - fl * 49) * 4;
            const float4* hp = (const float4*)(Hb + (size_t)(fc * 64 + fl) * NR + r4);
            float4 x = *hp;
            half4 v = {(_Float16)x.x, (_Float16)x.y, (_Float16)x.z, (_Float16)x.w};
            *(half4*)&Hv[fl * HS + r4] = v;
        }
        // zero-pad r in [196,208): K loop reads to 208
        for (int idx = tid; idx < 64 * 6; idx += 256) {
            int fl = idx / 6;
            int rr = NR + (idx - fl * 6) * 2;
            *(unsigned int*)&Hv[fl * HS + rr] = 0u;
        }
        __syncthreads();
        floatx16 o0, o1;
#pragma unroll
        for (int k = 0; k < 16; ++k) { o0[k] = 0.0f; o1[k] = 0.0f; }
#pragma unroll
        for (int ks = 0; ks < 13; ++ks) {
            half8 a = *(const half8*)&P[(32 * mt + col) * PS + ks * 16 + hf * 8];
            half8 bb = *(const half8*)&Hv[myf * HS + ks * 16 + hf * 8];
            if (ks & 1) o1 = MFMA(a, bb, o1);
            else        o0 = MFMA(a, bb, o0);
        }
        int f = fc * 64 + myf;
#pragma unroll
        for (int j = 0; j < 16; ++j) {
            int row = 32 * mt + (j & 3) + 8 * (j >> 2) + 4 * hf;
            int i = i_base + row;
            if (i < NI) out[((size_t)b * NI + i) * NF + f] = o0[j] + o1[j];
        }
    }
}

extern "C" void kernel_launch(void* const* d_in, const int* in_sizes, int n_in,
                              void* d_out, int out_size, void* d_ws, size_t ws_size,
                              hipStream_t stream) {
    const float* h_r  = (const float*)d_in[0];   // (256, 512, 196)
    const float* vecs = (const float*)d_in[1];   // (1000, 300)
    const float* w_g  = (const float*)d_in[2];   // (300, 512)
    float* out = (float*)d_out;                  // (256, 1000, 512) fp32

    _Float16* qh = (_Float16*)d_ws;              // [1024][512] fp16 hi
    _Float16* ql = qh + (size_t)IPAD * NF;       // [1024][512] fp16 lo

    hipLaunchKernelGGL(qsplit_kernel, dim3(128), dim3(256), 0, stream, vecs, w_g, qh, ql);
    hipLaunchKernelGGL(attn_kernel, dim3(16, 256), dim3(256), 0, stream, h_r, qh, ql, out);
}